// Round 7
// baseline (293.032 us; speedup 1.0000x reference)
//
#include <hip/hip_runtime.h>
#include <math.h>

typedef __bf16 bf16;
typedef bf16 bf16x8 __attribute__((ext_vector_type(8)));
typedef bf16 bf16x4 __attribute__((ext_vector_type(4)));
typedef float f32x4 __attribute__((ext_vector_type(4)));

// Problem constants
#define T_DIM 1024
#define B_DIM 4
#define E_DIM 512
#define H_DIM 8
#define HD_DIM 64
#define BH_DIM 32
#define SPLIT 4            // split-S factor for flash attention
#define S_PER (T_DIM / SPLIT)

__device__ __forceinline__ f32x4 mfma16(bf16x8 a, bf16x8 b, f32x4 c) {
    return __builtin_amdgcn_mfma_f32_16x16x32_bf16(a, b, c, 0, 0, 0);
}

__device__ __forceinline__ bf16x4 cvt4(f32x4 v) {
    bf16x4 o;
    o[0] = (bf16)v[0]; o[1] = (bf16)v[1]; o[2] = (bf16)v[2]; o[3] = (bf16)v[3];
    return o;
}

// ---------------------------------------------------------------------------
// Convert query[2^21], win[768K], wout[256K] fp32 -> bf16 in one launch.
// ---------------------------------------------------------------------------
#define CVT_Q_V   524288   // 2^21 / 4
#define CVT_W1_V  196608   // 786432 / 4
__global__ __launch_bounds__(256)
void cvt_all(const float* __restrict__ q, const float* __restrict__ w1,
             const float* __restrict__ w2, bf16* __restrict__ qo,
             bf16* __restrict__ w1o, bf16* __restrict__ w2o) {
    long v = (long)blockIdx.x * 256 + threadIdx.x;
    const float* src; bf16* dst;
    if (v < CVT_Q_V)                { src = q;  dst = qo; }
    else if (v < CVT_Q_V + CVT_W1_V){ v -= CVT_Q_V;  src = w1; dst = w1o; }
    else                            { v -= CVT_Q_V + CVT_W1_V; src = w2; dst = w2o; }
    f32x4 f = *(const f32x4*)(src + v * 4);
    *(bf16x4*)(dst + v * 4) = cvt4(f);
}

// ---------------------------------------------------------------------------
// C = A * Bt^T + bias.  A:[M,K] bf16 row-major, Bt:[N,K] bf16 row-major.
// Register-prefetch 2-phase K-loop.  Tiles shrunk for occupancy: A and the
// weights are L2-resident, so re-read cost is nil while blocks/CU doubles.
// MODE 0: out[m*N+n] = v (fp32)
// MODE 1: qkv scatter; q scaled 1/8 -> qb[bh][t][hd], kb[bh][t][hd],
//         V TRANSPOSED -> vb[bh][hd][t].
// ---------------------------------------------------------------------------
template<int TM, int TN, int MODE>
__global__ __launch_bounds__(256)
void gemm_t(const bf16* __restrict__ A, const bf16* __restrict__ Bt,
            const float* __restrict__ bias, int K, int N,
            float* __restrict__ out, bf16* __restrict__ qb,
            bf16* __restrict__ kb, bf16* __restrict__ vb) {
    constexpr int FM = TM / 32, FN = TN / 32;
    constexpr int PA = TM / 64, PB = TN / 64;
    __shared__ __align__(16) bf16 As[TM * 72];
    __shared__ __align__(16) bf16 Bs[TN * 72];
    const int tid  = threadIdx.x;
    const int lane = tid & 63;
    const int wave = tid >> 6;
    const int quad = lane >> 4;
    const int l15  = lane & 15;
    const int wm = wave & 1, wn = wave >> 1;
    const int m0 = blockIdx.x * TM, n0 = blockIdx.y * TN;

    f32x4 acc[FM][FN] = {};

    const int sr = tid >> 2;          // 0..63
    const int sc = (tid & 3) * 16;    // 0,16,32,48 (bf16 elems)

    // Preload k-tile 0 into registers
    bf16x8 ra[PA][2], rb[PB][2];
#pragma unroll
    for (int p = 0; p < PA; p++) {
        const bf16* src = &A[(long)(m0 + p * 64 + sr) * K + sc];
        ra[p][0] = *(const bf16x8*)(src);
        ra[p][1] = *(const bf16x8*)(src + 8);
    }
#pragma unroll
    for (int p = 0; p < PB; p++) {
        const bf16* src = &Bt[(long)(n0 + p * 64 + sr) * K + sc];
        rb[p][0] = *(const bf16x8*)(src);
        rb[p][1] = *(const bf16x8*)(src + 8);
    }

    for (int k0 = 0; k0 < K; k0 += 64) {
        __syncthreads();               // previous iteration's LDS reads done
#pragma unroll
        for (int p = 0; p < PA; p++) {
            *(bf16x8*)&As[(p * 64 + sr) * 72 + sc]     = ra[p][0];
            *(bf16x8*)&As[(p * 64 + sr) * 72 + sc + 8] = ra[p][1];
        }
#pragma unroll
        for (int p = 0; p < PB; p++) {
            *(bf16x8*)&Bs[(p * 64 + sr) * 72 + sc]     = rb[p][0];
            *(bf16x8*)&Bs[(p * 64 + sr) * 72 + sc + 8] = rb[p][1];
        }
        __syncthreads();               // staging visible

        // Issue next k-tile's global loads (retire during MFMA below)
        if (k0 + 64 < K) {
            const int kn = k0 + 64;
#pragma unroll
            for (int p = 0; p < PA; p++) {
                const bf16* src = &A[(long)(m0 + p * 64 + sr) * K + kn + sc];
                ra[p][0] = *(const bf16x8*)(src);
                ra[p][1] = *(const bf16x8*)(src + 8);
            }
#pragma unroll
            for (int p = 0; p < PB; p++) {
                const bf16* src = &Bt[(long)(n0 + p * 64 + sr) * K + kn + sc];
                rb[p][0] = *(const bf16x8*)(src);
                rb[p][1] = *(const bf16x8*)(src + 8);
            }
        }

#pragma unroll
        for (int kk = 0; kk < 64; kk += 32) {
            bf16x8 af[FM], bfr[FN];
#pragma unroll
            for (int mb = 0; mb < FM; mb++)
                af[mb] = *(const bf16x8*)&As[(wm * (TM / 2) + mb * 16 + l15) * 72 + kk + quad * 8];
#pragma unroll
            for (int nb = 0; nb < FN; nb++)
                bfr[nb] = *(const bf16x8*)&Bs[(wn * (TN / 2) + nb * 16 + l15) * 72 + kk + quad * 8];
#pragma unroll
            for (int mb = 0; mb < FM; mb++)
#pragma unroll
                for (int nb = 0; nb < FN; nb++)
                    acc[mb][nb] = mfma16(af[mb], bfr[nb], acc[mb][nb]);
        }
    }

    // Epilogue.  C/D layout: col = lane&15 (n), row = quad*4 + r (m).
#pragma unroll
    for (int mb = 0; mb < FM; mb++) {
#pragma unroll
        for (int nb = 0; nb < FN; nb++) {
            int n = n0 + wn * (TN / 2) + nb * 16 + l15;
            float bv = bias[n];
#pragma unroll
            for (int r = 0; r < 4; r++) {
                int m = m0 + wm * (TM / 2) + mb * 16 + quad * 4 + r;
                float v = acc[mb][nb][r] + bv;
                if (MODE == 0) {
                    out[(long)m * N + n] = v;
                } else {
                    int t = m >> 2, b = m & 3;
                    int sec = n >> 9, j = n & 511;
                    int h = j >> 6, hd = j & 63;
                    int bh = b * 8 + h;
                    if (sec == 0)
                        qb[((long)bh * T_DIM + t) * HD_DIM + hd] = (bf16)(v * 0.125f);
                    else if (sec == 1)
                        kb[((long)bh * T_DIM + t) * HD_DIM + hd] = (bf16)v;
                    else
                        vb[((long)bh * HD_DIM + hd) * T_DIM + t] = (bf16)v;  // transposed
                }
            }
        }
    }
}

// ---------------------------------------------------------------------------
// Split-S flash attention, ALL 8 HEADS PER BLOCK, bias fused from dist.
// Block = (b, 16-row q-tile, split); 4 waves, wave w owns heads 2w, 2w+1.
// Per s-tile the block reads dist[b][t0:16][st:st+64][0:8] as 16 fully-
// contiguous 2KB rows (perfect coalescing, every byte used exactly once, no
// inter-block sharing required), transposes to LDS bias[h][t][s] bf16, and
// each wave consumes its own heads' slabs in the softmax.  This removes the
// standalone bias_transpose kernel AND the 128 MB bias_t write+read.
// K/V fragments load direct from global (8 MB total, L2-resident).
// Partial (unnormalized) O + lsum per split; logits bounded -> partials
// combine by plain addition.
// ---------------------------------------------------------------------------
__global__ __launch_bounds__(256)
void attn_kernel(const bf16* __restrict__ qb, const bf16* __restrict__ kb,
                 const bf16* __restrict__ vb, const float* __restrict__ dist,
                 float* __restrict__ po, float* __restrict__ pl) {
    __shared__ __align__(16) bf16 Bs[8 * 1152];     // bias [h][16][72]
    __shared__ __align__(16) bf16 Ps[4 * 16 * 72];  // per-wave P staging
    const int tid  = threadIdx.x;
    const int lane = tid & 63;
    const int wave = tid >> 6;
    const int quad = lane >> 4;
    const int l15  = lane & 15;
    const int bid  = blockIdx.x;
    const int b    = bid & 3;
    const int qt   = (bid >> 2) & 63;   // 64 q-tiles of 16 rows
    const int split = bid >> 8;         // 0..SPLIT-1
    const int s0   = split * S_PER;
    const int t0   = qt * 16;

    // Q fragments for this wave's two heads (A-operand: row=l15, k=quad*8)
    bf16x8 qa[2][2];
#pragma unroll
    for (int hi = 0; hi < 2; hi++) {
        const int bh = b * 8 + wave * 2 + hi;
        const bf16* qp = &qb[((long)bh * T_DIM + t0 + l15) * HD_DIM];
        qa[hi][0] = *(const bf16x8*)(qp + quad * 8);
        qa[hi][1] = *(const bf16x8*)(qp + 32 + quad * 8);
    }

    f32x4 oacc[2][4] = {};
    float lsum[2][4] = {{0.f,0.f,0.f,0.f},{0.f,0.f,0.f,0.f}};

    // dist staging map: thread -> (t_loc = tid>>4, 32 floats = 4 s x 8 h)
    const int t_loc = tid >> 4;
    const int s_loc = (tid & 15) * 4;
    const float* dsrc = dist + ((long)(b * 1024 + t0 + t_loc) * 1024 + s0) * 8 + s_loc * 8;

    // Prefetch dist tile 0 (32 floats, coalesced)
    f32x4 dv[8];
#pragma unroll
    for (int j = 0; j < 8; j++) dv[j] = *(const f32x4*)(dsrc + j * 4);

    for (int st = s0; st < s0 + S_PER; st += 64) {
        __syncthreads();               // previous tile's bias reads done
        // Scatter prefetched dist into LDS bias[h][t][s] (bf16)
        {
            const float* vv = (const float*)dv;
#pragma unroll
            for (int h = 0; h < 8; h++) {
                bf16x4 w;
                w[0] = (bf16)vv[0 * 8 + h];
                w[1] = (bf16)vv[1 * 8 + h];
                w[2] = (bf16)vv[2 * 8 + h];
                w[3] = (bf16)vv[3 * 8 + h];
                *(bf16x4*)&Bs[h * 1152 + t_loc * 72 + s_loc] = w;
            }
        }
        __syncthreads();               // bias visible to all waves

        // Prefetch next dist tile (hidden behind this tile's compute)
        if (st + 64 < s0 + S_PER) {
            const float* dn = dsrc + (long)(st + 64 - s0) * 8;
#pragma unroll
            for (int j = 0; j < 8; j++) dv[j] = *(const f32x4*)(dn + j * 4);
        }

        bf16* pw = &Ps[wave * 16 * 72];
#pragma unroll
        for (int hi = 0; hi < 2; hi++) {
            const int h  = wave * 2 + hi;
            const int bh = b * 8 + h;

            // S = Q*K^T (M=16 t-rows, N=64 s, K=64 hd); K direct from global
            f32x4 sacc[4] = {};
            __builtin_amdgcn_s_setprio(1);
#pragma unroll
            for (int kk = 0; kk < 64; kk += 32) {
#pragma unroll
                for (int nb = 0; nb < 4; nb++) {
                    bf16x8 kf = *(const bf16x8*)&kb[((long)bh * T_DIM + st + nb * 16 + l15) * HD_DIM + kk + quad * 8];
                    sacc[nb] = mfma16(qa[hi][kk >> 5], kf, sacc[nb]);
                }
            }
            __builtin_amdgcn_s_setprio(0);

            // exp(S + bias); per-lane denominator; P -> LDS (A layout)
#pragma unroll
            for (int r = 0; r < 4; r++) {
                float rs = 0.f;
#pragma unroll
                for (int nb = 0; nb < 4; nb++) {
                    float d = (float)Bs[h * 1152 + (quad * 4 + r) * 72 + nb * 16 + l15];
                    float p = __expf(sacc[nb][r] + d);
                    rs += p;
                    pw[(quad * 4 + r) * 72 + nb * 16 + l15] = (bf16)p;
                }
                lsum[hi][r] += rs;
            }

            // O += P * V; V^T direct from global.  pw wave-private: same-wave
            // DS ordering suffices (also across the hi=0 -> hi=1 reuse).
            __builtin_amdgcn_s_setprio(1);
#pragma unroll
            for (int kk = 0; kk < 64; kk += 32) {
                bf16x8 ap = *(const bf16x8*)&pw[l15 * 72 + kk + quad * 8];
#pragma unroll
                for (int nb = 0; nb < 4; nb++) {
                    bf16x8 vf = *(const bf16x8*)&vb[((long)bh * HD_DIM + nb * 16 + l15) * T_DIM + st + kk + quad * 8];
                    oacc[hi][nb] = mfma16(ap, vf, oacc[hi][nb]);
                }
            }
            __builtin_amdgcn_s_setprio(0);
        }
    }

    // Reduce denominators across the 16 lanes of each quad-row
#pragma unroll
    for (int hi = 0; hi < 2; hi++)
#pragma unroll
        for (int r = 0; r < 4; r++) {
#pragma unroll
            for (int msk = 1; msk < 16; msk <<= 1)
                lsum[hi][r] += __shfl_xor(lsum[hi][r], msk);
        }

    // Epilogue: write UNNORMALIZED partial O (fp32) + partial lsum.
    float* pob = po + (long)split * (BH_DIM * T_DIM * HD_DIM);
#pragma unroll
    for (int hi = 0; hi < 2; hi++) {
        const int bh = b * 8 + wave * 2 + hi;
#pragma unroll
        for (int nb = 0; nb < 4; nb++)
#pragma unroll
            for (int r = 0; r < 4; r++)
                pob[((long)bh * T_DIM + t0 + quad * 4 + r) * HD_DIM + nb * 16 + l15] = oacc[hi][nb][r];
    }
    if (l15 == 0) {
#pragma unroll
        for (int hi = 0; hi < 2; hi++) {
            const int bh = b * 8 + wave * 2 + hi;
#pragma unroll
            for (int r = 0; r < 4; r++)
                pl[(long)split * (BH_DIM * T_DIM) + bh * T_DIM + t0 + quad * 4 + r] = lsum[hi][r];
        }
    }
}

// ---------------------------------------------------------------------------
// Combine SPLIT partials: O = sum(po), l = sum(pl); ctxb = bf16(O/l).
// ---------------------------------------------------------------------------
__global__ __launch_bounds__(256)
void combine(const float* __restrict__ po, const float* __restrict__ pl,
             bf16* __restrict__ ctxb) {
    const int gid = blockIdx.x * 256 + threadIdx.x;  // 0..524287
    const int hd4 = gid & 15;
    const int t   = (gid >> 4) & 1023;
    const int bh  = gid >> 14;
    const long base = ((long)bh * T_DIM + t) * HD_DIM + hd4 * 4;
    f32x4 o = {};
    float l = 0.f;
#pragma unroll
    for (int s = 0; s < SPLIT; s++) {
        o += *(const f32x4*)&po[(long)s * (BH_DIM * T_DIM * HD_DIM) + base];
        l += pl[(long)s * (BH_DIM * T_DIM) + bh * T_DIM + t];
    }
    float inv = 1.f / l;
    f32x4 r = o * inv;
    const int b = bh >> 3, hh = bh & 7;
    *(bf16x4*)&ctxb[((long)t * B_DIM + b) * E_DIM + hh * HD_DIM + hd4 * 4] = cvt4(r);
}

// ---------------------------------------------------------------------------
extern "C" void kernel_launch(void* const* d_in, const int* in_sizes, int n_in,
                              void* d_out, int out_size, void* d_ws, size_t ws_size,
                              hipStream_t stream) {
    const float* query = (const float*)d_in[0];   // [T,B,E]
    const float* dist  = (const float*)d_in[1];   // [B,T,T,H]
    const float* win   = (const float*)d_in[2];   // [3E,E]
    const float* bin   = (const float*)d_in[3];   // [3E]
    const float* wout  = (const float*)d_in[4];   // [E,E]
    const float* bout  = (const float*)d_in[5];   // [E]
    float* out = (float*)d_out;                   // [T,B,E]

    bf16* qb   = (bf16*)d_ws;                     // [BH,T,HD]
    bf16* kb   = qb + (1 << 21);                  // [BH,T,HD]
    bf16* vb   = kb + (1 << 21);                  // [BH,HD,T] (transposed)
    bf16* qbf  = vb + (1 << 21);                  // query bf16 [2^21]
    bf16* w1bf = qbf + (1 << 21);                 // win bf16 [768K]
    bf16* w2bf = w1bf + 786432;                   // wout bf16 [256K]
    bf16* ctxb = w2bf + 262144;                   // ctx bf16 [2^21]
    float* po  = (float*)(ctxb + (1 << 21));      // [SPLIT,BH,T,HD] fp32 (32 MB)
    float* pl  = po + (long)SPLIT * BH_DIM * T_DIM * HD_DIM;  // [SPLIT,BH,T]

    // Convert fp32 inputs to bf16 (one launch, ~4 us)
    cvt_all<<<dim3(3072), 256, 0, stream>>>(query, win, wout, qbf, w1bf, w2bf);
    // QKV in-projection: M=4096, N=1536, K=512, 64x128 tiles -> 768 blocks
    gemm_t<64, 128, 1><<<dim3(64, 12), 256, 0, stream>>>(
        qbf, w1bf, bin, 512, 1536, nullptr, qb, kb, vb);
    // Split-S attention, all heads per block: 4 b x 64 qtiles x SPLIT blocks
    attn_kernel<<<dim3(4 * 64 * SPLIT), 256, 0, stream>>>(qb, kb, vb, dist, po, pl);
    // Combine partials -> ctxb (bf16)
    combine<<<dim3(2048), 256, 0, stream>>>(po, pl, ctxb);
    // Out-projection: M=4096, N=512, K=512, 64x64 tiles -> 512 blocks
    gemm_t<64, 64, 0><<<dim3(64, 8), 256, 0, stream>>>(
        ctxb, w2bf, bout, 512, 512, out, nullptr, nullptr, nullptr);
}

// Round 13
// 277.692 us; speedup vs baseline: 1.0552x; 1.0552x over previous
//
#include <hip/hip_runtime.h>
#include <math.h>

typedef __bf16 bf16;
typedef bf16 bf16x8 __attribute__((ext_vector_type(8)));
typedef bf16 bf16x4 __attribute__((ext_vector_type(4)));
typedef float f32x4 __attribute__((ext_vector_type(4)));

// Problem constants
#define T_DIM 1024
#define B_DIM 4
#define E_DIM 512
#define H_DIM 8
#define HD_DIM 64
#define BH_DIM 32
#define SPLIT 4            // split-S factor for flash attention
#define S_PER (T_DIM / SPLIT)

__device__ __forceinline__ f32x4 mfma16(bf16x8 a, bf16x8 b, f32x4 c) {
    return __builtin_amdgcn_mfma_f32_16x16x32_bf16(a, b, c, 0, 0, 0);
}

__device__ __forceinline__ bf16x4 cvt4(f32x4 v) {
    bf16x4 o;
    o[0] = (bf16)v[0]; o[1] = (bf16)v[1]; o[2] = (bf16)v[2]; o[3] = (bf16)v[3];
    return o;
}

// ---------------------------------------------------------------------------
// prep: fused {bias transpose} + {fp32->bf16 conversions} in ONE launch.
// Blocks 0..4095: dist[B,T,T,H] fp32 -> bias_t[BH,T,T] bf16 (block per (b,t),
//   coalesced read of 32 contiguous floats/thread, LDS transpose, coalesced
//   bf16x8 writes).  Blocks 4096..7167: cvt query/win/wout -> bf16.
// ---------------------------------------------------------------------------
#define CVT_Q_V   524288   // 2^21 / 4
#define CVT_W1_V  196608   // 786432 / 4
__global__ __launch_bounds__(256)
void prep(const float* __restrict__ dist, bf16* __restrict__ bias_t,
          const float* __restrict__ q, const float* __restrict__ w1,
          const float* __restrict__ w2, bf16* __restrict__ qo,
          bf16* __restrict__ w1o, bf16* __restrict__ w2o) {
    __shared__ __align__(16) bf16 tile[8 * 1032];
    if (blockIdx.x >= 4096) {
        // ---- conversion part (3072 blocks) ----
        long v = (long)(blockIdx.x - 4096) * 256 + threadIdx.x;
        const float* src; bf16* dst;
        if (v < CVT_Q_V)                { src = q;  dst = qo; }
        else if (v < CVT_Q_V + CVT_W1_V){ v -= CVT_Q_V;  src = w1; dst = w1o; }
        else                            { v -= CVT_Q_V + CVT_W1_V; src = w2; dst = w2o; }
        f32x4 f = *(const f32x4*)(src + v * 4);
        *(bf16x4*)(dst + v * 4) = cvt4(f);
        return;
    }
    // ---- transpose part (4096 blocks) ----
    const int bt = blockIdx.x;              // b*1024 + t
    const int b = bt >> 10, t = bt & 1023;
    const int tid = threadIdx.x;
    const float* src = dist + ((long)bt << 13) + tid * 32;
    const int s0 = tid * 4;
    float v[32];
#pragma unroll
    for (int j = 0; j < 8; j++) {
        f32x4 f = *(const f32x4*)(src + j * 4);
        v[j * 4 + 0] = f[0]; v[j * 4 + 1] = f[1];
        v[j * 4 + 2] = f[2]; v[j * 4 + 3] = f[3];
    }
#pragma unroll
    for (int h = 0; h < 8; h++)
#pragma unroll
        for (int si = 0; si < 4; si++)
            tile[h * 1032 + s0 + si] = (bf16)v[si * 8 + h];
    __syncthreads();
#pragma unroll
    for (int rep = 0; rep < 4; rep++) {
        int slot = rep * 256 + tid;         // 0..1023
        int h = slot >> 7;                  // 0..7
        int sc = (slot & 127) * 8;          // s-chunk
        bf16x8 o = *(const bf16x8*)&tile[h * 1032 + sc];
        *(bf16x8*)&bias_t[((long)(b * 8 + h) * T_DIM + t) * T_DIM + sc] = o;
    }
}

// ---------------------------------------------------------------------------
// C = A * Bt^T + bias.  A:[M,K] bf16 row-major, Bt:[N,K] bf16 row-major.
// Double-buffered LDS, ONE barrier per k-step:
//   ds_write buf[i&1] -> barrier -> issue loads(i+1) -> ds_read+MFMA.
// The old 2-barrier loop force-drained the prefetch loads at the next
// iteration's first __syncthreads (s_waitcnt vmcnt(0) before s_barrier);
// here loads are issued AFTER the barrier and consumed by a per-wave vmcnt
// wait before next iteration's ds_write - they stay in flight across the
// whole MFMA phase.  WAR hazard removed by buffer flip (buf[i&1]'s last
// readers finished before the previous barrier).
// MODE 0: out[m*N+n] = v (fp32)
// MODE 1: qkv scatter; q scaled 1/8 -> qb[bh][t][hd], kb[bh][t][hd],
//         V TRANSPOSED -> vb[bh][hd][t].
// ---------------------------------------------------------------------------
template<int TM, int TN, int MODE>
__global__ __launch_bounds__(256)
void gemm_t(const bf16* __restrict__ A, const bf16* __restrict__ Bt,
            const float* __restrict__ bias, int K, int N,
            float* __restrict__ out, bf16* __restrict__ qb,
            bf16* __restrict__ kb, bf16* __restrict__ vb) {
    constexpr int FM = TM / 32, FN = TN / 32;
    constexpr int PA = TM / 64, PB = TN / 64;
    __shared__ __align__(16) bf16 As[2][TM * 72];
    __shared__ __align__(16) bf16 Bs[2][TN * 72];
    const int tid  = threadIdx.x;
    const int lane = tid & 63;
    const int wave = tid >> 6;
    const int quad = lane >> 4;
    const int l15  = lane & 15;
    const int wm = wave & 1, wn = wave >> 1;
    const int m0 = blockIdx.x * TM, n0 = blockIdx.y * TN;

    f32x4 acc[FM][FN] = {};

    const int sr = tid >> 2;          // 0..63
    const int sc = (tid & 3) * 16;    // 0,16,32,48 (bf16 elems)

    // Prologue: load k-tile 0 into registers
    bf16x8 ra[PA][2], rb[PB][2];
#pragma unroll
    for (int p = 0; p < PA; p++) {
        const bf16* src = &A[(long)(m0 + p * 64 + sr) * K + sc];
        ra[p][0] = *(const bf16x8*)(src);
        ra[p][1] = *(const bf16x8*)(src + 8);
    }
#pragma unroll
    for (int p = 0; p < PB; p++) {
        const bf16* src = &Bt[(long)(n0 + p * 64 + sr) * K + sc];
        rb[p][0] = *(const bf16x8*)(src);
        rb[p][1] = *(const bf16x8*)(src + 8);
    }

    const int NK = K >> 6;
    for (int i = 0; i < NK; i++) {
        const int cur = i & 1;
        bf16* as = As[cur];
        bf16* bs = Bs[cur];
        // Stage tile i (per-wave vmcnt wait on the loads, not a full drain)
#pragma unroll
        for (int p = 0; p < PA; p++) {
            *(bf16x8*)&as[(p * 64 + sr) * 72 + sc]     = ra[p][0];
            *(bf16x8*)&as[(p * 64 + sr) * 72 + sc + 8] = ra[p][1];
        }
#pragma unroll
        for (int p = 0; p < PB; p++) {
            *(bf16x8*)&bs[(p * 64 + sr) * 72 + sc]     = rb[p][0];
            *(bf16x8*)&bs[(p * 64 + sr) * 72 + sc + 8] = rb[p][1];
        }
        __syncthreads();               // single barrier: staging visible

        // Issue next k-tile's loads AFTER the barrier (no forced drain;
        // they retire under the ds_read+MFMA phase below)
        if (i + 1 < NK) {
            const int kn = (i + 1) << 6;
#pragma unroll
            for (int p = 0; p < PA; p++) {
                const bf16* src = &A[(long)(m0 + p * 64 + sr) * K + kn + sc];
                ra[p][0] = *(const bf16x8*)(src);
                ra[p][1] = *(const bf16x8*)(src + 8);
            }
#pragma unroll
            for (int p = 0; p < PB; p++) {
                const bf16* src = &Bt[(long)(n0 + p * 64 + sr) * K + kn + sc];
                rb[p][0] = *(const bf16x8*)(src);
                rb[p][1] = *(const bf16x8*)(src + 8);
            }
        }

#pragma unroll
        for (int kk = 0; kk < 64; kk += 32) {
            bf16x8 af[FM], bfr[FN];
#pragma unroll
            for (int mb = 0; mb < FM; mb++)
                af[mb] = *(const bf16x8*)&as[(wm * (TM / 2) + mb * 16 + l15) * 72 + kk + quad * 8];
#pragma unroll
            for (int nb = 0; nb < FN; nb++)
                bfr[nb] = *(const bf16x8*)&bs[(wn * (TN / 2) + nb * 16 + l15) * 72 + kk + quad * 8];
#pragma unroll
            for (int mb = 0; mb < FM; mb++)
#pragma unroll
                for (int nb = 0; nb < FN; nb++)
                    acc[mb][nb] = mfma16(af[mb], bfr[nb], acc[mb][nb]);
        }
        // No second barrier: next iteration writes buf[cur^1], whose last
        // readers (iteration i-1) finished before this iteration's barrier.
    }

    // Epilogue.  C/D layout: col = lane&15 (n), row = quad*4 + r (m).
#pragma unroll
    for (int mb = 0; mb < FM; mb++) {
#pragma unroll
        for (int nb = 0; nb < FN; nb++) {
            int n = n0 + wn * (TN / 2) + nb * 16 + l15;
            float bv = bias[n];
#pragma unroll
            for (int r = 0; r < 4; r++) {
                int m = m0 + wm * (TM / 2) + mb * 16 + quad * 4 + r;
                float v = acc[mb][nb][r] + bv;
                if (MODE == 0) {
                    out[(long)m * N + n] = v;
                } else {
                    int t = m >> 2, b = m & 3;
                    int sec = n >> 9, j = n & 511;
                    int h = j >> 6, hd = j & 63;
                    int bh = b * 8 + h;
                    if (sec == 0)
                        qb[((long)bh * T_DIM + t) * HD_DIM + hd] = (bf16)(v * 0.125f);
                    else if (sec == 1)
                        kb[((long)bh * T_DIM + t) * HD_DIM + hd] = (bf16)v;
                    else
                        vb[((long)bh * HD_DIM + hd) * T_DIM + t] = (bf16)v;  // transposed
                }
            }
        }
    }
}

// ---------------------------------------------------------------------------
// Split-S flash attention, bias from PRE-TRANSPOSED bias_t (bf16 [BH,T,T]).
// Bias loads go straight to registers (~4 granules/instruction); K/V staged
// into LDS with coalesced bf16x8 loads; all operands prefetched one tile
// ahead.  Partial (unnormalized) O + lsum per split; logits bounded so
// partials combine by plain addition.  (Proven R4 configuration.)
// ---------------------------------------------------------------------------
__global__ __launch_bounds__(256)
void attn_kernel(const bf16* __restrict__ qb, const bf16* __restrict__ kb,
                 const bf16* __restrict__ vb, const bf16* __restrict__ bias_t,
                 float* __restrict__ po, float* __restrict__ pl) {
    __shared__ __align__(16) bf16 Ks[64 * 72];
    __shared__ __align__(16) bf16 Vts[64 * 72];
    __shared__ __align__(16) bf16 Ps[4 * 16 * 72];
    const int tid  = threadIdx.x;
    const int lane = tid & 63;
    const int wave = tid >> 6;
    const int quad = lane >> 4;
    const int l15  = lane & 15;
    const int bid  = blockIdx.x;
    const int bh   = (bid >> 4) & 31;  // 0..31
    const int qt   = bid & 15;         // 0..15
    const int split = bid >> 9;        // 0..SPLIT-1
    const int s0   = split * S_PER;
    const int qrow = qt * 64 + wave * 16 + l15;

    bf16x8 qa0 = *(const bf16x8*)&qb[((long)bh * T_DIM + qrow) * HD_DIM + quad * 8];
    bf16x8 qa1 = *(const bf16x8*)&qb[((long)bh * T_DIM + qrow) * HD_DIM + 32 + quad * 8];

    f32x4 oacc[4] = {};
    float lsum[4] = {0.f, 0.f, 0.f, 0.f};

    const int r0 = tid >> 3;          // 0..31
    const int c0 = (tid & 7) * 8;     // 0..56

    // Per-lane bias base: bias_t[bh][qt*64 + wave*16 + quad*4 + r][s]
    const bf16* dp = bias_t + ((long)bh * T_DIM + qt * 64 + wave * 16 + quad * 4) * T_DIM;

    // Prefetch tile 0 of this split
    bf16x8 pk0, pk1, pv0, pv1;
    float pbias[16];
    pk0 = *(const bf16x8*)&kb[((long)bh * T_DIM + s0 + r0) * HD_DIM + c0];
    pk1 = *(const bf16x8*)&kb[((long)bh * T_DIM + s0 + r0 + 32) * HD_DIM + c0];
    pv0 = *(const bf16x8*)&vb[((long)bh * HD_DIM + r0) * T_DIM + s0 + c0];
    pv1 = *(const bf16x8*)&vb[((long)bh * HD_DIM + r0 + 32) * T_DIM + s0 + c0];
#pragma unroll
    for (int r = 0; r < 4; r++)
#pragma unroll
        for (int nb = 0; nb < 4; nb++)
            pbias[r * 4 + nb] = (float)dp[(long)r * T_DIM + s0 + nb * 16 + l15];

    for (int st = s0; st < s0 + S_PER; st += 64) {
        __syncthreads();               // previous iteration's LDS reads done
        *(bf16x8*)&Ks[r0 * 72 + c0]         = pk0;
        *(bf16x8*)&Ks[(r0 + 32) * 72 + c0]  = pk1;
        *(bf16x8*)&Vts[r0 * 72 + c0]        = pv0;
        *(bf16x8*)&Vts[(r0 + 32) * 72 + c0] = pv1;
        __syncthreads();               // staging visible

        // Prefetch next K/V tile (hidden behind this tile's compute)
        if (st + 64 < s0 + S_PER) {
            const int sn = st + 64;
            pk0 = *(const bf16x8*)&kb[((long)bh * T_DIM + sn + r0) * HD_DIM + c0];
            pk1 = *(const bf16x8*)&kb[((long)bh * T_DIM + sn + r0 + 32) * HD_DIM + c0];
            pv0 = *(const bf16x8*)&vb[((long)bh * HD_DIM + r0) * T_DIM + sn + c0];
            pv1 = *(const bf16x8*)&vb[((long)bh * HD_DIM + r0 + 32) * T_DIM + sn + c0];
        }

        // S = Q*K^T  (M=16 q-rows, N=64 s, K=64 hd)
        f32x4 sacc[4] = {};
        __builtin_amdgcn_s_setprio(1);
#pragma unroll
        for (int kk = 0; kk < 64; kk += 32) {
            bf16x8 a = (kk == 0) ? qa0 : qa1;
#pragma unroll
            for (int nb = 0; nb < 4; nb++) {
                bf16x8 bfr = *(const bf16x8*)&Ks[(nb * 16 + l15) * 72 + kk + quad * 8];
                sacc[nb] = mfma16(a, bfr, sacc[nb]);
            }
        }
        __builtin_amdgcn_s_setprio(0);

        // exp(S + bias); accumulate per-lane denominator; P -> LDS (A layout)
        bf16* pw = &Ps[wave * 16 * 72];
#pragma unroll
        for (int r = 0; r < 4; r++) {
            float rs = 0.f;
#pragma unroll
            for (int nb = 0; nb < 4; nb++) {
                float p = __expf(sacc[nb][r] + pbias[r * 4 + nb]);
                rs += p;
                pw[(quad * 4 + r) * 72 + nb * 16 + l15] = (bf16)p;
            }
            lsum[r] += rs;
        }

        // Prefetch next bias tile (latency hidden by PV + next staging + QK)
        if (st + 64 < s0 + S_PER) {
            const int sn = st + 64;
#pragma unroll
            for (int r = 0; r < 4; r++)
#pragma unroll
                for (int nb = 0; nb < 4; nb++)
                    pbias[r * 4 + nb] = (float)dp[(long)r * T_DIM + sn + nb * 16 + l15];
        }

        // O += P * V.  pw wave-private; same-wave DS ordering suffices.
        __builtin_amdgcn_s_setprio(1);
#pragma unroll
        for (int kk = 0; kk < 64; kk += 32) {
            bf16x8 ap = *(const bf16x8*)&pw[l15 * 72 + kk + quad * 8];
#pragma unroll
            for (int nb = 0; nb < 4; nb++) {
                bf16x8 bv2 = *(const bf16x8*)&Vts[(nb * 16 + l15) * 72 + kk + quad * 8];
                oacc[nb] = mfma16(ap, bv2, oacc[nb]);
            }
        }
        __builtin_amdgcn_s_setprio(0);
    }

    // Reduce denominators across the 16 lanes of each quad-row
#pragma unroll
    for (int r = 0; r < 4; r++) {
#pragma unroll
        for (int msk = 1; msk < 16; msk <<= 1)
            lsum[r] += __shfl_xor(lsum[r], msk);
    }

    // Epilogue: write UNNORMALIZED partial O (fp32) + partial lsum.
    float* pob = po + (long)split * (BH_DIM * T_DIM * HD_DIM);
#pragma unroll
    for (int nb = 0; nb < 4; nb++) {
#pragma unroll
        for (int r = 0; r < 4; r++) {
            int t  = qt * 64 + wave * 16 + quad * 4 + r;
            int hd = nb * 16 + l15;
            pob[((long)bh * T_DIM + t) * HD_DIM + hd] = oacc[nb][r];
        }
    }
    if (l15 == 0) {
#pragma unroll
        for (int r = 0; r < 4; r++) {
            int t = qt * 64 + wave * 16 + quad * 4 + r;
            pl[(long)split * (BH_DIM * T_DIM) + bh * T_DIM + t] = lsum[r];
        }
    }
}

// ---------------------------------------------------------------------------
// Combine SPLIT partials: O = sum(po), l = sum(pl); ctxb = bf16(O/l).
// ---------------------------------------------------------------------------
__global__ __launch_bounds__(256)
void combine(const float* __restrict__ po, const float* __restrict__ pl,
             bf16* __restrict__ ctxb) {
    const int gid = blockIdx.x * 256 + threadIdx.x;  // 0..524287
    const int hd4 = gid & 15;
    const int t   = (gid >> 4) & 1023;
    const int bh  = gid >> 14;
    const long base = ((long)bh * T_DIM + t) * HD_DIM + hd4 * 4;
    f32x4 o = {};
    float l = 0.f;
#pragma unroll
    for (int s = 0; s < SPLIT; s++) {
        o += *(const f32x4*)&po[(long)s * (BH_DIM * T_DIM * HD_DIM) + base];
        l += pl[(long)s * (BH_DIM * T_DIM) + bh * T_DIM + t];
    }
    float inv = 1.f / l;
    f32x4 r = o * inv;
    const int b = bh >> 3, hh = bh & 7;
    *(bf16x4*)&ctxb[((long)t * B_DIM + b) * E_DIM + hh * HD_DIM + hd4 * 4] = cvt4(r);
}

// ---------------------------------------------------------------------------
extern "C" void kernel_launch(void* const* d_in, const int* in_sizes, int n_in,
                              void* d_out, int out_size, void* d_ws, size_t ws_size,
                              hipStream_t stream) {
    const float* query = (const float*)d_in[0];   // [T,B,E]
    const float* dist  = (const float*)d_in[1];   // [B,T,T,H]
    const float* win   = (const float*)d_in[2];   // [3E,E]
    const float* bin   = (const float*)d_in[3];   // [3E]
    const float* wout  = (const float*)d_in[4];   // [E,E]
    const float* bout  = (const float*)d_in[5];   // [E]
    float* out = (float*)d_out;                   // [T,B,E]

    bf16* bias_t = (bf16*)d_ws;                   // [BH,T,T] bf16 = 64 MiB
    bf16* qb   = bias_t + ((long)BH_DIM * T_DIM * T_DIM);
    bf16* kb   = qb + (1 << 21);                  // [BH,T,HD]
    bf16* vb   = kb + (1 << 21);                  // [BH,HD,T] (transposed)
    bf16* qbf  = vb + (1 << 21);                  // query bf16 [2^21]
    bf16* w1bf = qbf + (1 << 21);                 // win bf16 [768K]
    bf16* w2bf = w1bf + 786432;                   // wout bf16 [256K]
    bf16* ctxb = w2bf + 262144;                   // ctx bf16 [2^21]
    float* po  = (float*)(ctxb + (1 << 21));      // [SPLIT,BH,T,HD] fp32 (32 MB)
    float* pl  = po + (long)SPLIT * BH_DIM * T_DIM * HD_DIM;  // [SPLIT,BH,T]

    // Fused transpose + conversions: 4096 transpose blocks + 3072 cvt blocks
    prep<<<dim3(7168), 256, 0, stream>>>(dist, bias_t, query, win, wout,
                                         qbf, w1bf, w2bf);
    // QKV in-projection: M=4096, N=1536, K=512, 64x192 tiles -> 512 blocks
    // (exactly 2 blocks/CU, no tail round; dbuf LDS = 73.7 KB)
    gemm_t<64, 192, 1><<<dim3(64, 8), 256, 0, stream>>>(
        qbf, w1bf, bin, 512, 1536, nullptr, qb, kb, vb);
    // Split-S attention: 512*SPLIT blocks
    attn_kernel<<<dim3(512 * SPLIT), 256, 0, stream>>>(qb, kb, vb, bias_t, po, pl);
    // Combine partials -> ctxb (bf16)
    combine<<<dim3(2048), 256, 0, stream>>>(po, pl, ctxb);
    // Out-projection: M=4096, N=512, K=512, 64x64 tiles -> 512 blocks
    gemm_t<64, 64, 0><<<dim3(64, 8), 256, 0, stream>>>(
        ctxb, w2bf, bout, 512, 512, out, nullptr, nullptr, nullptr);
}

// Round 15
// 268.089 us; speedup vs baseline: 1.0930x; 1.0358x over previous
//
#include <hip/hip_runtime.h>
#include <math.h>

typedef __bf16 bf16;
typedef bf16 bf16x8 __attribute__((ext_vector_type(8)));
typedef bf16 bf16x4 __attribute__((ext_vector_type(4)));
typedef float f32x4 __attribute__((ext_vector_type(4)));

// Problem constants
#define T_DIM 1024
#define B_DIM 4
#define E_DIM 512
#define H_DIM 8
#define HD_DIM 64
#define BH_DIM 32

__device__ __forceinline__ f32x4 mfma16(bf16x8 a, bf16x8 b, f32x4 c) {
    return __builtin_amdgcn_mfma_f32_16x16x32_bf16(a, b, c, 0, 0, 0);
}

__device__ __forceinline__ bf16x4 cvt4(f32x4 v) {
    bf16x4 o;
    o[0] = (bf16)v[0]; o[1] = (bf16)v[1]; o[2] = (bf16)v[2]; o[3] = (bf16)v[3];
    return o;
}

// ---------------------------------------------------------------------------
// prep: fused {bias transpose} + {fp32->bf16 conversions} in ONE launch.
// Blocks 0..4095: dist[B,T,T,H] fp32 -> bias_t[BH,T,T] bf16 (block per (b,t),
//   coalesced read of 32 contiguous floats/thread, LDS transpose, coalesced
//   bf16x8 writes).  Blocks 4096..7167: cvt query/win/wout -> bf16.
// (Proven R13 configuration.)
// ---------------------------------------------------------------------------
#define CVT_Q_V   524288   // 2^21 / 4
#define CVT_W1_V  196608   // 786432 / 4
__global__ __launch_bounds__(256)
void prep(const float* __restrict__ dist, bf16* __restrict__ bias_t,
          const float* __restrict__ q, const float* __restrict__ w1,
          const float* __restrict__ w2, bf16* __restrict__ qo,
          bf16* __restrict__ w1o, bf16* __restrict__ w2o) {
    __shared__ __align__(16) bf16 tile[8 * 1032];
    if (blockIdx.x >= 4096) {
        // ---- conversion part (3072 blocks) ----
        long v = (long)(blockIdx.x - 4096) * 256 + threadIdx.x;
        const float* src; bf16* dst;
        if (v < CVT_Q_V)                { src = q;  dst = qo; }
        else if (v < CVT_Q_V + CVT_W1_V){ v -= CVT_Q_V;  src = w1; dst = w1o; }
        else                            { v -= CVT_Q_V + CVT_W1_V; src = w2; dst = w2o; }
        f32x4 f = *(const f32x4*)(src + v * 4);
        *(bf16x4*)(dst + v * 4) = cvt4(f);
        return;
    }
    // ---- transpose part (4096 blocks) ----
    const int bt = blockIdx.x;              // b*1024 + t
    const int b = bt >> 10, t = bt & 1023;
    const int tid = threadIdx.x;
    const float* src = dist + ((long)bt << 13) + tid * 32;
    const int s0 = tid * 4;
    float v[32];
#pragma unroll
    for (int j = 0; j < 8; j++) {
        f32x4 f = *(const f32x4*)(src + j * 4);
        v[j * 4 + 0] = f[0]; v[j * 4 + 1] = f[1];
        v[j * 4 + 2] = f[2]; v[j * 4 + 3] = f[3];
    }
#pragma unroll
    for (int h = 0; h < 8; h++)
#pragma unroll
        for (int si = 0; si < 4; si++)
            tile[h * 1032 + s0 + si] = (bf16)v[si * 8 + h];
    __syncthreads();
#pragma unroll
    for (int rep = 0; rep < 4; rep++) {
        int slot = rep * 256 + tid;         // 0..1023
        int h = slot >> 7;                  // 0..7
        int sc = (slot & 127) * 8;          // s-chunk
        bf16x8 o = *(const bf16x8*)&tile[h * 1032 + sc];
        *(bf16x8*)&bias_t[((long)(b * 8 + h) * T_DIM + t) * T_DIM + sc] = o;
    }
}

// ---------------------------------------------------------------------------
// C = A * Bt^T + bias.  A:[M,K] bf16 row-major, Bt:[N,K] bf16 row-major.
// Double-buffered LDS, ONE barrier per k-step (proven R13 configuration):
//   ds_write buf[i&1] -> barrier -> issue loads(i+1) -> ds_read+MFMA.
// MODE 0: out[m*N+n] = v (fp32)
// MODE 1: qkv scatter; q scaled 1/8 -> qb[bh][t][hd], kb[bh][t][hd],
//         V TRANSPOSED -> vb[bh][hd][t].
// ---------------------------------------------------------------------------
template<int TM, int TN, int MODE>
__global__ __launch_bounds__(256)
void gemm_t(const bf16* __restrict__ A, const bf16* __restrict__ Bt,
            const float* __restrict__ bias, int K, int N,
            float* __restrict__ out, bf16* __restrict__ qb,
            bf16* __restrict__ kb, bf16* __restrict__ vb) {
    constexpr int FM = TM / 32, FN = TN / 32;
    constexpr int PA = TM / 64, PB = TN / 64;
    __shared__ __align__(16) bf16 As[2][TM * 72];
    __shared__ __align__(16) bf16 Bs[2][TN * 72];
    const int tid  = threadIdx.x;
    const int lane = tid & 63;
    const int wave = tid >> 6;
    const int quad = lane >> 4;
    const int l15  = lane & 15;
    const int wm = wave & 1, wn = wave >> 1;
    const int m0 = blockIdx.x * TM, n0 = blockIdx.y * TN;

    f32x4 acc[FM][FN] = {};

    const int sr = tid >> 2;          // 0..63
    const int sc = (tid & 3) * 16;    // 0,16,32,48 (bf16 elems)

    // Prologue: load k-tile 0 into registers
    bf16x8 ra[PA][2], rb[PB][2];
#pragma unroll
    for (int p = 0; p < PA; p++) {
        const bf16* src = &A[(long)(m0 + p * 64 + sr) * K + sc];
        ra[p][0] = *(const bf16x8*)(src);
        ra[p][1] = *(const bf16x8*)(src + 8);
    }
#pragma unroll
    for (int p = 0; p < PB; p++) {
        const bf16* src = &Bt[(long)(n0 + p * 64 + sr) * K + sc];
        rb[p][0] = *(const bf16x8*)(src);
        rb[p][1] = *(const bf16x8*)(src + 8);
    }

    const int NK = K >> 6;
    for (int i = 0; i < NK; i++) {
        const int cur = i & 1;
        bf16* as = As[cur];
        bf16* bs = Bs[cur];
        // Stage tile i (per-wave vmcnt wait on the loads, not a full drain)
#pragma unroll
        for (int p = 0; p < PA; p++) {
            *(bf16x8*)&as[(p * 64 + sr) * 72 + sc]     = ra[p][0];
            *(bf16x8*)&as[(p * 64 + sr) * 72 + sc + 8] = ra[p][1];
        }
#pragma unroll
        for (int p = 0; p < PB; p++) {
            *(bf16x8*)&bs[(p * 64 + sr) * 72 + sc]     = rb[p][0];
            *(bf16x8*)&bs[(p * 64 + sr) * 72 + sc + 8] = rb[p][1];
        }
        __syncthreads();               // single barrier: staging visible

        // Issue next k-tile's loads AFTER the barrier (no forced drain;
        // they retire under the ds_read+MFMA phase below)
        if (i + 1 < NK) {
            const int kn = (i + 1) << 6;
#pragma unroll
            for (int p = 0; p < PA; p++) {
                const bf16* src = &A[(long)(m0 + p * 64 + sr) * K + kn + sc];
                ra[p][0] = *(const bf16x8*)(src);
                ra[p][1] = *(const bf16x8*)(src + 8);
            }
#pragma unroll
            for (int p = 0; p < PB; p++) {
                const bf16* src = &Bt[(long)(n0 + p * 64 + sr) * K + kn + sc];
                rb[p][0] = *(const bf16x8*)(src);
                rb[p][1] = *(const bf16x8*)(src + 8);
            }
        }

#pragma unroll
        for (int kk = 0; kk < 64; kk += 32) {
            bf16x8 af[FM], bfr[FN];
#pragma unroll
            for (int mb = 0; mb < FM; mb++)
                af[mb] = *(const bf16x8*)&as[(wm * (TM / 2) + mb * 16 + l15) * 72 + kk + quad * 8];
#pragma unroll
            for (int nb = 0; nb < FN; nb++)
                bfr[nb] = *(const bf16x8*)&bs[(wn * (TN / 2) + nb * 16 + l15) * 72 + kk + quad * 8];
#pragma unroll
            for (int mb = 0; mb < FM; mb++)
#pragma unroll
                for (int nb = 0; nb < FN; nb++)
                    acc[mb][nb] = mfma16(af[mb], bfr[nb], acc[mb][nb]);
        }
        // No second barrier: next iteration writes buf[cur^1], whose last
        // readers (iteration i-1) finished before this iteration's barrier.
    }

    // Epilogue.  C/D layout: col = lane&15 (n), row = quad*4 + r (m).
#pragma unroll
    for (int mb = 0; mb < FM; mb++) {
#pragma unroll
        for (int nb = 0; nb < FN; nb++) {
            int n = n0 + wn * (TN / 2) + nb * 16 + l15;
            float bv = bias[n];
#pragma unroll
            for (int r = 0; r < 4; r++) {
                int m = m0 + wm * (TM / 2) + mb * 16 + quad * 4 + r;
                float v = acc[mb][nb][r] + bv;
                if (MODE == 0) {
                    out[(long)m * N + n] = v;
                } else {
                    int t = m >> 2, b = m & 3;
                    int sec = n >> 9, j = n & 511;
                    int h = j >> 6, hd = j & 63;
                    int bh = b * 8 + h;
                    if (sec == 0)
                        qb[((long)bh * T_DIM + t) * HD_DIM + hd] = (bf16)(v * 0.125f);
                    else if (sec == 1)
                        kb[((long)bh * T_DIM + t) * HD_DIM + hd] = (bf16)v;
                    else
                        vb[((long)bh * HD_DIM + hd) * T_DIM + t] = (bf16)v;  // transposed
                }
            }
        }
    }
}

// ---------------------------------------------------------------------------
// Flash attention, SPLIT=1 (full s-loop per block), bias from PRE-TRANSPOSED
// bias_t (bf16 [BH,T,T]) straight to registers (~4 granules/instruction);
// K/V staged into LDS with coalesced bf16x8 loads; all operands prefetched
// one tile ahead.  Epilogue normalizes and writes ctxb bf16 DIRECTLY —
// no split partials (32MB W + 32MB R + combine kernel removed; R2 proved
// extra split-occupancy doesn't help this transaction-bound kernel).
// ---------------------------------------------------------------------------
__global__ __launch_bounds__(256)
void attn_kernel(const bf16* __restrict__ qb, const bf16* __restrict__ kb,
                 const bf16* __restrict__ vb, const bf16* __restrict__ bias_t,
                 bf16* __restrict__ ctxb) {
    __shared__ __align__(16) bf16 Ks[64 * 72];
    __shared__ __align__(16) bf16 Vts[64 * 72];
    __shared__ __align__(16) bf16 Ps[4 * 16 * 72];
    const int tid  = threadIdx.x;
    const int lane = tid & 63;
    const int wave = tid >> 6;
    const int quad = lane >> 4;
    const int l15  = lane & 15;
    const int bid  = blockIdx.x;
    const int bh   = bid >> 4;         // 0..31
    const int qt   = bid & 15;         // 0..15
    const int b    = bh >> 3, h = bh & 7;
    const int qrow = qt * 64 + wave * 16 + l15;

    bf16x8 qa0 = *(const bf16x8*)&qb[((long)bh * T_DIM + qrow) * HD_DIM + quad * 8];
    bf16x8 qa1 = *(const bf16x8*)&qb[((long)bh * T_DIM + qrow) * HD_DIM + 32 + quad * 8];

    f32x4 oacc[4] = {};
    float lsum[4] = {0.f, 0.f, 0.f, 0.f};

    const int r0 = tid >> 3;          // 0..31
    const int c0 = (tid & 7) * 8;     // 0..56

    // Per-lane bias base: bias_t[bh][qt*64 + wave*16 + quad*4 + r][s]
    const bf16* dp = bias_t + ((long)bh * T_DIM + qt * 64 + wave * 16 + quad * 4) * T_DIM;

    // Prefetch tile 0
    bf16x8 pk0, pk1, pv0, pv1;
    float pbias[16];
    pk0 = *(const bf16x8*)&kb[((long)bh * T_DIM + r0) * HD_DIM + c0];
    pk1 = *(const bf16x8*)&kb[((long)bh * T_DIM + r0 + 32) * HD_DIM + c0];
    pv0 = *(const bf16x8*)&vb[((long)bh * HD_DIM + r0) * T_DIM + c0];
    pv1 = *(const bf16x8*)&vb[((long)bh * HD_DIM + r0 + 32) * T_DIM + c0];
#pragma unroll
    for (int r = 0; r < 4; r++)
#pragma unroll
        for (int nb = 0; nb < 4; nb++)
            pbias[r * 4 + nb] = (float)dp[(long)r * T_DIM + nb * 16 + l15];

    for (int st = 0; st < T_DIM; st += 64) {
        __syncthreads();               // previous iteration's LDS reads done
        *(bf16x8*)&Ks[r0 * 72 + c0]         = pk0;
        *(bf16x8*)&Ks[(r0 + 32) * 72 + c0]  = pk1;
        *(bf16x8*)&Vts[r0 * 72 + c0]        = pv0;
        *(bf16x8*)&Vts[(r0 + 32) * 72 + c0] = pv1;
        __syncthreads();               // staging visible

        // Prefetch next K/V tile (hidden behind this tile's compute)
        if (st + 64 < T_DIM) {
            const int sn = st + 64;
            pk0 = *(const bf16x8*)&kb[((long)bh * T_DIM + sn + r0) * HD_DIM + c0];
            pk1 = *(const bf16x8*)&kb[((long)bh * T_DIM + sn + r0 + 32) * HD_DIM + c0];
            pv0 = *(const bf16x8*)&vb[((long)bh * HD_DIM + r0) * T_DIM + sn + c0];
            pv1 = *(const bf16x8*)&vb[((long)bh * HD_DIM + r0 + 32) * T_DIM + sn + c0];
        }

        // S = Q*K^T  (M=16 q-rows, N=64 s, K=64 hd)
        f32x4 sacc[4] = {};
        __builtin_amdgcn_s_setprio(1);
#pragma unroll
        for (int kk = 0; kk < 64; kk += 32) {
            bf16x8 a = (kk == 0) ? qa0 : qa1;
#pragma unroll
            for (int nb = 0; nb < 4; nb++) {
                bf16x8 bfr = *(const bf16x8*)&Ks[(nb * 16 + l15) * 72 + kk + quad * 8];
                sacc[nb] = mfma16(a, bfr, sacc[nb]);
            }
        }
        __builtin_amdgcn_s_setprio(0);

        // exp(S + bias); accumulate per-lane denominator; P -> LDS (A layout)
        bf16* pw = &Ps[wave * 16 * 72];
#pragma unroll
        for (int r = 0; r < 4; r++) {
            float rs = 0.f;
#pragma unroll
            for (int nb = 0; nb < 4; nb++) {
                float p = __expf(sacc[nb][r] + pbias[r * 4 + nb]);
                rs += p;
                pw[(quad * 4 + r) * 72 + nb * 16 + l15] = (bf16)p;
            }
            lsum[r] += rs;
        }

        // Prefetch next bias tile (latency hidden by PV + next staging + QK)
        if (st + 64 < T_DIM) {
            const int sn = st + 64;
#pragma unroll
            for (int r = 0; r < 4; r++)
#pragma unroll
                for (int nb = 0; nb < 4; nb++)
                    pbias[r * 4 + nb] = (float)dp[(long)r * T_DIM + sn + nb * 16 + l15];
        }

        // O += P * V.  pw wave-private; same-wave DS ordering suffices.
        __builtin_amdgcn_s_setprio(1);
#pragma unroll
        for (int kk = 0; kk < 64; kk += 32) {
            bf16x8 ap = *(const bf16x8*)&pw[l15 * 72 + kk + quad * 8];
#pragma unroll
            for (int nb = 0; nb < 4; nb++) {
                bf16x8 bv2 = *(const bf16x8*)&Vts[(nb * 16 + l15) * 72 + kk + quad * 8];
                oacc[nb] = mfma16(ap, bv2, oacc[nb]);
            }
        }
        __builtin_amdgcn_s_setprio(0);
    }

    // Reduce denominators across the 16 lanes of each quad-row
#pragma unroll
    for (int r = 0; r < 4; r++) {
#pragma unroll
        for (int msk = 1; msk < 16; msk <<= 1)
            lsum[r] += __shfl_xor(lsum[r], msk);
    }

    // Epilogue: normalize and write ctxb[t][b][h*64+hd] (bf16, consumed
    // directly by the out-projection GEMM)
#pragma unroll
    for (int nb = 0; nb < 4; nb++) {
#pragma unroll
        for (int r = 0; r < 4; r++) {
            int t  = qt * 64 + wave * 16 + quad * 4 + r;
            int hd = nb * 16 + l15;
            float o = oacc[nb][r] / lsum[r];
            ctxb[((long)t * B_DIM + b) * E_DIM + h * HD_DIM + hd] = (bf16)o;
        }
    }
}

// ---------------------------------------------------------------------------
extern "C" void kernel_launch(void* const* d_in, const int* in_sizes, int n_in,
                              void* d_out, int out_size, void* d_ws, size_t ws_size,
                              hipStream_t stream) {
    const float* query = (const float*)d_in[0];   // [T,B,E]
    const float* dist  = (const float*)d_in[1];   // [B,T,T,H]
    const float* win   = (const float*)d_in[2];   // [3E,E]
    const float* bin   = (const float*)d_in[3];   // [3E]
    const float* wout  = (const float*)d_in[4];   // [E,E]
    const float* bout  = (const float*)d_in[5];   // [E]
    float* out = (float*)d_out;                   // [T,B,E]

    bf16* bias_t = (bf16*)d_ws;                   // [BH,T,T] bf16 = 64 MiB
    bf16* qb   = bias_t + ((long)BH_DIM * T_DIM * T_DIM);
    bf16* kb   = qb + (1 << 21);                  // [BH,T,HD]
    bf16* vb   = kb + (1 << 21);                  // [BH,HD,T] (transposed)
    bf16* qbf  = vb + (1 << 21);                  // query bf16 [2^21]
    bf16* w1bf = qbf + (1 << 21);                 // win bf16 [768K]
    bf16* w2bf = w1bf + 786432;                   // wout bf16 [256K]
    bf16* ctxb = w2bf + 262144;                   // ctx bf16 [2^21]

    // Fused transpose + conversions: 4096 transpose blocks + 3072 cvt blocks
    prep<<<dim3(7168), 256, 0, stream>>>(dist, bias_t, query, win, wout,
                                         qbf, w1bf, w2bf);
    // QKV in-projection: M=4096, N=1536, K=512, 64x192 tiles -> 512 blocks
    gemm_t<64, 192, 1><<<dim3(64, 8), 256, 0, stream>>>(
        qbf, w1bf, bin, 512, 1536, nullptr, qb, kb, vb);
    // Attention (SPLIT=1, direct bf16 ctx write): 512 blocks
    attn_kernel<<<dim3(512), 256, 0, stream>>>(qb, kb, vb, bias_t, ctxb);
    // Out-projection: M=4096, N=512, K=512, 64x64 tiles -> 512 blocks
    gemm_t<64, 64, 0><<<dim3(64, 8), 256, 0, stream>>>(
        ctxb, w2bf, bout, 512, 512, out, nullptr, nullptr, nullptr);
}